// Round 4
// baseline (4605.073 us; speedup 1.0000x reference)
//
#include <hip/hip_runtime.h>
#include <hip/hip_bf16.h>

#define L_ 8
#define B_ 8
#define T_ 1024
#define C_ 768
#define H_ 12
#define D_HEAD 64
#define V_ 1024
#define FF_ 3072
#define M_ (B_ * T_)  // 8192 rows

typedef __bf16 bf16x8 __attribute__((ext_vector_type(8)));
typedef float f32x4 __attribute__((ext_vector_type(4)));

typedef const __attribute__((address_space(1))) void* as1cvp;
typedef __attribute__((address_space(3))) void* as3vp;

__device__ __forceinline__ void async16(const void* g, void* l) {
  __builtin_amdgcn_global_load_lds((as1cvp)g, (as3vp)l, 16, 0, 0);
}

__device__ __forceinline__ float bf2f(unsigned short u) {
  union { unsigned u32; float f; } c; c.u32 = ((unsigned)u) << 16; return c.f;
}

__device__ __forceinline__ unsigned short f2bf(float f) {
  __hip_bfloat16 h = __float2bfloat16(f);
  return *(unsigned short*)&h;
}

__device__ __forceinline__ float gelu_f(float x) {
  return 0.5f * x * (1.0f + erff(x * 0.70710678118654752f));
}

// ---------------------------------------------------------------------------
// Embedding: h[row, c] = embed[x[row]][c] + pos[row % T][c]; also bf16 copy.
// ---------------------------------------------------------------------------
__global__ __launch_bounds__(256) void embed_kernel(
    const int* __restrict__ x, const float* __restrict__ emb,
    const float* __restrict__ pos, float* __restrict__ h,
    __hip_bfloat16* __restrict__ hb) {
  int row = blockIdx.x;
  int t = row & (T_ - 1);
  int id = x[row];
#pragma unroll
  for (int j = 0; j < 3; ++j) {
    int c = threadIdx.x + j * 256;
    float v = emb[(size_t)id * C_ + c] + pos[(size_t)t * C_ + c];
    h[(size_t)row * C_ + c] = v;
    hb[(size_t)row * C_ + c] = __float2bfloat16(v);
  }
}

// ---------------------------------------------------------------------------
// Transpose + cast: W (K x N, f32) -> Wt (N x K, bf16)
// ---------------------------------------------------------------------------
__global__ void transpose_cast(const float* __restrict__ W,
                               __hip_bfloat16* __restrict__ Wt, int K, int N) {
  __shared__ float tile[32][33];
  int nb = blockIdx.x * 32, kb = blockIdx.y * 32;
  int tx = threadIdx.x, ty = threadIdx.y;  // 32 x 8
#pragma unroll
  for (int r = 0; r < 4; ++r)
    tile[ty + r * 8][tx] = W[(size_t)(kb + ty + r * 8) * N + nb + tx];
  __syncthreads();
#pragma unroll
  for (int r = 0; r < 4; ++r)
    Wt[(size_t)(nb + ty + r * 8) * K + kb + tx] =
        __float2bfloat16(tile[tx][ty + r * 8]);
}

// Two matrices of identical shape in one dispatch (z selects).
__global__ void transpose_cast2(const float* __restrict__ Wa,
                                __hip_bfloat16* __restrict__ Wta,
                                const float* __restrict__ Wb,
                                __hip_bfloat16* __restrict__ Wtb, int K, int N) {
  __shared__ float tile[32][33];
  const float* W = blockIdx.z ? Wb : Wa;
  __hip_bfloat16* Wt = blockIdx.z ? Wtb : Wta;
  int nb = blockIdx.x * 32, kb = blockIdx.y * 32;
  int tx = threadIdx.x, ty = threadIdx.y;  // 32 x 8
#pragma unroll
  for (int r = 0; r < 4; ++r)
    tile[ty + r * 8][tx] = W[(size_t)(kb + ty + r * 8) * N + nb + tx];
  __syncthreads();
#pragma unroll
  for (int r = 0; r < 4; ++r)
    Wt[(size_t)(nb + ty + r * 8) * K + kb + tx] =
        __float2bfloat16(tile[tx][ty + r * 8]);
}

// ---------------------------------------------------------------------------
// V transpose per (b,head): qkv V-part (t, d) -> vT[(bh*64+d)][t], bf16.
// ---------------------------------------------------------------------------
__global__ __launch_bounds__(256) void vtrans_kernel(
    const __hip_bfloat16* __restrict__ qkv, __hip_bfloat16* __restrict__ vT) {
  __shared__ __hip_bfloat16 tile[32][33];
  int bh = blockIdx.z;
  int b = bh / H_, hh = bh % H_;
  int t0 = blockIdx.x * 32, d0 = blockIdx.y * 32;
  int tx = threadIdx.x, ty = threadIdx.y;  // 32 x 8
  const __hip_bfloat16* src =
      qkv + (size_t)b * T_ * (3 * C_) + 2 * C_ + hh * D_HEAD;
#pragma unroll
  for (int r = 0; r < 4; ++r)
    tile[ty + r * 8][tx] = src[(size_t)(t0 + ty + r * 8) * (3 * C_) + d0 + tx];
  __syncthreads();
  __hip_bfloat16* dst = vT + (size_t)bh * D_HEAD * T_;
#pragma unroll
  for (int r = 0; r < 4; ++r)
    dst[(size_t)(d0 + ty + r * 8) * T_ + t0 + tx] = tile[tx][ty + r * 8];
}

// ---------------------------------------------------------------------------
// GEMM: C[M,N] = A[M,K](bf16) @ Bt[N,K](bf16)^T + bias, opt GELU, f32/bf16 out
// 128x128 tile, BK=32, 256 threads (4 waves, 2x2), mfma_f32_16x16x32_bf16.
// ---------------------------------------------------------------------------
template <int ACT_GELU, int OUT_BF16>
__global__ __launch_bounds__(256, 2) void gemm_bt(
    const __hip_bfloat16* __restrict__ A, const __hip_bfloat16* __restrict__ Bt,
    const float* __restrict__ bias, void* __restrict__ Cv, int M, int N, int K) {
  __shared__ __align__(16) __hip_bfloat16 As[128 * 32];
  __shared__ __align__(16) __hip_bfloat16 Bs[128 * 32];
  const int tid = threadIdx.x;
  const int lane = tid & 63, wv = tid >> 6;
  const int lane4 = lane & 15, quad = lane >> 4;
  const int wr = wv >> 1, wc = wv & 1;
  const int bm = blockIdx.y * 128, bn = blockIdx.x * 128;

  const int r0 = tid >> 2, kc0 = (tid & 3) * 8;
  const __hip_bfloat16* gA0 = A + (size_t)(bm + r0) * K + kc0;
  const __hip_bfloat16* gA1 = gA0 + (size_t)64 * K;
  const __hip_bfloat16* gB0 = Bt + (size_t)(bn + r0) * K + kc0;
  const __hip_bfloat16* gB1 = gB0 + (size_t)64 * K;
  __hip_bfloat16* lA0 = As + tid * 8;
  __hip_bfloat16* lA1 = As + (tid + 256) * 8;
  __hip_bfloat16* lB0 = Bs + tid * 8;
  __hip_bfloat16* lB1 = Bs + (tid + 256) * 8;

  f32x4 acc[4][4] = {};

  for (int k0 = 0; k0 < K; k0 += 32) {
    async16(gA0 + k0, lA0);
    async16(gA1 + k0, lA1);
    async16(gB0 + k0, lB0);
    async16(gB1 + k0, lB1);
    __syncthreads();
    bf16x8 af[4], bfv[4];
#pragma unroll
    for (int i = 0; i < 4; ++i)
      af[i] = *(const bf16x8*)(As + (wr * 64 + i * 16 + lane4) * 32 + quad * 8);
#pragma unroll
    for (int j = 0; j < 4; ++j)
      bfv[j] = *(const bf16x8*)(Bs + (wc * 64 + j * 16 + lane4) * 32 + quad * 8);
#pragma unroll
    for (int i = 0; i < 4; ++i)
#pragma unroll
      for (int j = 0; j < 4; ++j)
        acc[i][j] = __builtin_amdgcn_mfma_f32_16x16x32_bf16(af[i], bfv[j],
                                                            acc[i][j], 0, 0, 0);
    __syncthreads();
  }

#pragma unroll
  for (int i = 0; i < 4; ++i) {
    int row0 = bm + wr * 64 + i * 16 + quad * 4;
#pragma unroll
    for (int j = 0; j < 4; ++j) {
      int col = bn + wc * 64 + j * 16 + lane4;
      float bv = bias[col];
#pragma unroll
      for (int r = 0; r < 4; ++r) {
        float v = acc[i][j][r] + bv;
        if (ACT_GELU) v = gelu_f(v);
        size_t off = (size_t)(row0 + r) * N + col;
        if (OUT_BF16)
          ((__hip_bfloat16*)Cv)[off] = __float2bfloat16(v);
        else
          ((float*)Cv)[off] = v;
      }
    }
  }
}

// ---------------------------------------------------------------------------
// Barrier-free MFMA flash attention.
// Sᵀ = mfma(K_frag, Q_frag): col=lane4=q, row=key. Softmax per lane (1 q),
// cross-quad reduce via 2 shuffles. P bounced through per-wave private LDS
// into B-fragment; V read pre-transposed (vT) as A-fragment. O accumulated
// transposed; per-wave LDS bounce at end for coalesced stores. NO barriers.
// ---------------------------------------------------------------------------
__global__ __launch_bounds__(256) void attn_mfma(
    const __hip_bfloat16* __restrict__ qkv, const __hip_bfloat16* __restrict__ vT,
    __hip_bfloat16* __restrict__ y) {
  __shared__ __align__(16) __hip_bfloat16 Ps[4][16][72];  // per-wave [q][key]

  const int tid = threadIdx.x;
  const int lane = tid & 63, w = tid >> 6;
  const int lane4 = lane & 15, quad = lane >> 4;
  const int qt = gridDim.x - 1 - blockIdx.x;  // heavy tiles first
  const int bh = blockIdx.y;
  const int b = bh / H_, hh = bh % H_;
  const unsigned short* qk16 = (const unsigned short*)qkv;
  const unsigned short* vt16 = (const unsigned short*)vT;
  const size_t base = (size_t)b * T_ * (3 * C_) + hh * D_HEAD;

  union FragU { bf16x8 v; unsigned short s[8]; uint4 q; };

  // Q fragment (B operand: n=q=lane4, k=dim=quad*8+j), pre-scaled by 1/8
  FragU aq[2];
  {
    const unsigned short* qp =
        qk16 + base + (size_t)(qt * 64 + w * 16 + lane4) * (3 * C_) + C_ +
        quad * 8;
#pragma unroll
    for (int c = 0; c < 2; ++c) {
      FragU t;
      t.q = *(const uint4*)(qp + c * 32);
#pragma unroll
      for (int j = 0; j < 8; ++j) aq[c].s[j] = f2bf(bf2f(t.s[j]) * 0.125f);
    }
  }

  // K fragment base (A operand: m=key=lane4, k=dim=quad*8+j)
  const unsigned short* kbase = qk16 + base + (size_t)lane4 * (3 * C_) + quad * 8;
  // vT fragment base (A operand: m=dim=lane4, k=key=quad*8+j)
  const unsigned short* vbase =
      vt16 + ((size_t)bh * D_HEAD + lane4) * T_ + quad * 8;
  const size_t kstride = (size_t)64 * (3 * C_);  // keys per tile in qkv rows

  f32x4 o_acc[4] = {};   // Oᵀ: [ntd][r]: d = ntd*16+quad*4+r, q = lane4
  float m = -1e30f, l = 0.f;

  FragU kc[4][2], vc[4][2];
#pragma unroll
  for (int nt = 0; nt < 4; ++nt) {
    kc[nt][0].q = *(const uint4*)(kbase + (size_t)nt * 16 * (3 * C_));
    kc[nt][1].q = *(const uint4*)(kbase + (size_t)nt * 16 * (3 * C_) + 32);
    vc[nt][0].q = *(const uint4*)(vbase + (size_t)nt * 16 * T_);
    vc[nt][1].q = *(const uint4*)(vbase + (size_t)nt * 16 * T_ + 32);
  }

  for (int kt = 0; kt <= qt; ++kt) {
    // prefetch next tile (clamped)
    FragU kn[4][2], vn[4][2];
    {
      int ktn = (kt < qt) ? kt + 1 : qt;
      const unsigned short* kp = kbase + (size_t)ktn * kstride;
      const unsigned short* vp = vbase + ktn * 64;
#pragma unroll
      for (int nt = 0; nt < 4; ++nt) {
        kn[nt][0].q = *(const uint4*)(kp + (size_t)nt * 16 * (3 * C_));
        kn[nt][1].q = *(const uint4*)(kp + (size_t)nt * 16 * (3 * C_) + 32);
        vn[nt][0].q = *(const uint4*)(vp + (size_t)nt * 16 * T_);
        vn[nt][1].q = *(const uint4*)(vp + (size_t)nt * 16 * T_ + 32);
      }
    }

    // Sᵀ = K·Qᵀ  (rows=keys, cols=q)
    f32x4 sT[4] = {};
#pragma unroll
    for (int nt = 0; nt < 4; ++nt) {
      sT[nt] = __builtin_amdgcn_mfma_f32_16x16x32_bf16(kc[nt][0].v, aq[0].v,
                                                       sT[nt], 0, 0, 0);
      sT[nt] = __builtin_amdgcn_mfma_f32_16x16x32_bf16(kc[nt][1].v, aq[1].v,
                                                       sT[nt], 0, 0, 0);
    }

    // causal mask on diagonal tile: key_local = nt*16+quad*4+r, q_local = w*16+lane4
    if (kt == qt) {
      int ql = w * 16 + lane4;
#pragma unroll
      for (int nt = 0; nt < 4; ++nt)
#pragma unroll
        for (int r = 0; r < 4; ++r)
          if (nt * 16 + quad * 4 + r > ql) sT[nt][r] = -1e30f;
    }

    // online softmax: each lane owns one q (lane4); reduce in-lane + 2 shuffles
    float tm = sT[0][0];
#pragma unroll
    for (int nt = 0; nt < 4; ++nt)
#pragma unroll
      for (int r = 0; r < 4; ++r) tm = fmaxf(tm, sT[nt][r]);
    tm = fmaxf(tm, __shfl_xor(tm, 16));
    tm = fmaxf(tm, __shfl_xor(tm, 32));
    float mn = fmaxf(m, tm);
    float alpha = __expf(m - mn);
    m = mn;
    float p[4][4], ts = 0.f;
#pragma unroll
    for (int nt = 0; nt < 4; ++nt)
#pragma unroll
      for (int r = 0; r < 4; ++r) {
        float pv = __expf(sT[nt][r] - mn);
        p[nt][r] = pv;
        ts += pv;
      }
    ts += __shfl_xor(ts, 16);
    ts += __shfl_xor(ts, 32);
    l = l * alpha + ts;
#pragma unroll
    for (int nt = 0; nt < 4; ++nt)
#pragma unroll
      for (int r = 0; r < 4; ++r) o_acc[nt][r] *= alpha;

    // P -> per-wave LDS [q][key] (packed b32 writes); wave-internal ordering only
#pragma unroll
    for (int nt = 0; nt < 4; ++nt) {
      unsigned w01 = (unsigned)f2bf(p[nt][0]) | ((unsigned)f2bf(p[nt][1]) << 16);
      unsigned w23 = (unsigned)f2bf(p[nt][2]) | ((unsigned)f2bf(p[nt][3]) << 16);
      *(unsigned*)&Ps[w][lane4][nt * 16 + quad * 4] = w01;
      *(unsigned*)&Ps[w][lane4][nt * 16 + quad * 4 + 2] = w23;
    }
    FragU ap0, ap1;  // B operand: n=q=lane4, k=key=quad*8+j
    ap0.v = *(const bf16x8*)&Ps[w][lane4][quad * 8];
    ap1.v = *(const bf16x8*)&Ps[w][lane4][32 + quad * 8];

    // Oᵀ += Vᵀ·Pᵀ
#pragma unroll
    for (int nt = 0; nt < 4; ++nt) {
      o_acc[nt] = __builtin_amdgcn_mfma_f32_16x16x32_bf16(vc[nt][0].v, ap0.v,
                                                          o_acc[nt], 0, 0, 0);
      o_acc[nt] = __builtin_amdgcn_mfma_f32_16x16x32_bf16(vc[nt][1].v, ap1.v,
                                                          o_acc[nt], 0, 0, 0);
    }

    // rotate prefetch
#pragma unroll
    for (int nt = 0; nt < 4; ++nt) {
      kc[nt][0] = kn[nt][0];
      kc[nt][1] = kn[nt][1];
      vc[nt][0] = vn[nt][0];
      vc[nt][1] = vn[nt][1];
    }
  }

  // epilogue: Oᵀ -> per-wave LDS (bf16, [q][d]) -> coalesced global stores
  float inv = 1.f / l;
#pragma unroll
  for (int nt = 0; nt < 4; ++nt)
#pragma unroll
    for (int r = 0; r < 4; ++r)
      *(unsigned short*)&Ps[w][lane4][nt * 16 + quad * 4 + r] =
          f2bf(o_acc[nt][r] * inv);
  {
    int q = lane & 15, seg = lane >> 4;
    uint4 p0 = *(const uint4*)&Ps[w][q][seg * 16];
    uint4 p1 = *(const uint4*)&Ps[w][q][seg * 16 + 8];
    __hip_bfloat16* yp = y + (size_t)(b * T_ + qt * 64 + w * 16 + q) * C_ +
                         hh * D_HEAD + seg * 16;
    *(uint4*)yp = p0;
    *((uint4*)yp + 1) = p1;
  }
}

// ---------------------------------------------------------------------------
// h = h + LayerNorm(z) * g + beta ; also write bf16 copy of updated h.
// ---------------------------------------------------------------------------
__global__ __launch_bounds__(256) void resid_ln(
    float* __restrict__ h, const float* __restrict__ z,
    const float* __restrict__ g, const float* __restrict__ be,
    __hip_bfloat16* __restrict__ hb) {
  int row = blockIdx.x;
  int tid = threadIdx.x;
  const float* zr = z + (size_t)row * C_;
  float v[3], s = 0.f, s2 = 0.f;
#pragma unroll
  for (int j = 0; j < 3; ++j) {
    v[j] = zr[tid + 256 * j];
    s += v[j];
    s2 += v[j] * v[j];
  }
#pragma unroll
  for (int msk = 1; msk < 64; msk <<= 1) {
    s += __shfl_xor(s, msk);
    s2 += __shfl_xor(s2, msk);
  }
  __shared__ float red[8];
  int w = tid >> 6;
  if ((tid & 63) == 0) { red[w] = s; red[4 + w] = s2; }
  __syncthreads();
  s = red[0] + red[1] + red[2] + red[3];
  s2 = red[4] + red[5] + red[6] + red[7];
  float mu = s * (1.f / C_);
  float var = s2 * (1.f / C_) - mu * mu;
  float rstd = rsqrtf(var + 1e-5f);
  float* hr = h + (size_t)row * C_;
  __hip_bfloat16* hbr = hb + (size_t)row * C_;
#pragma unroll
  for (int j = 0; j < 3; ++j) {
    int c = tid + 256 * j;
    float nv = hr[c] + (v[j] - mu) * rstd * g[c] + be[c];
    hr[c] = nv;
    hbr[c] = __float2bfloat16(nv);
  }
}

// ---------------------------------------------------------------------------
extern "C" void kernel_launch(void* const* d_in, const int* in_sizes, int n_in,
                              void* d_out, int out_size, void* d_ws,
                              size_t ws_size, hipStream_t stream) {
  const int* x = (const int*)d_in[0];
  const float* embed = (const float*)d_in[1];
  const float* pos = (const float*)d_in[2];
  const float* Wqkv = (const float*)d_in[3];
  const float* bqkv = (const float*)d_in[4];
  const float* W1a = (const float*)d_in[5];
  const float* b1a = (const float*)d_in[6];
  const float* W2a = (const float*)d_in[7];
  const float* b2a = (const float*)d_in[8];
  const float* g1 = (const float*)d_in[9];
  const float* be1 = (const float*)d_in[10];
  const float* W1b = (const float*)d_in[11];
  const float* b1b = (const float*)d_in[12];
  const float* W2b = (const float*)d_in[13];
  const float* b2b = (const float*)d_in[14];
  const float* g2 = (const float*)d_in[15];
  const float* be2 = (const float*)d_in[16];
  const float* lmW = (const float*)d_in[17];
  const float* lmb = (const float*)d_in[18];
  float* out = (float*)d_out;

  char* p = (char*)d_ws;
  auto alloc = [&](size_t bytes) {
    void* r = (void*)p;
    p += (bytes + 255) & ~(size_t)255;
    return r;
  };
  float* h = (float*)alloc((size_t)M_ * C_ * 4);
  __hip_bfloat16* hb = (__hip_bfloat16*)alloc((size_t)M_ * C_ * 2);
  __hip_bfloat16* qkv = (__hip_bfloat16*)alloc((size_t)M_ * 3 * C_ * 2);
  __hip_bfloat16* vTb = (__hip_bfloat16*)alloc((size_t)B_ * H_ * D_HEAD * T_ * 2);
  __hip_bfloat16* ybuf = (__hip_bfloat16*)alloc((size_t)M_ * C_ * 2);
  __hip_bfloat16* ubuf = (__hip_bfloat16*)alloc((size_t)M_ * FF_ * 2);
  float* zbuf = (float*)alloc((size_t)M_ * C_ * 4);
  __hip_bfloat16* Wtqkv = (__hip_bfloat16*)alloc((size_t)(3 * C_) * C_ * 2);
  __hip_bfloat16* Wt1a = (__hip_bfloat16*)alloc((size_t)FF_ * C_ * 2);
  __hip_bfloat16* Wt1b = (__hip_bfloat16*)alloc((size_t)FF_ * C_ * 2);
  __hip_bfloat16* Wt2a = (__hip_bfloat16*)alloc((size_t)C_ * FF_ * 2);
  __hip_bfloat16* Wt2b = (__hip_bfloat16*)alloc((size_t)C_ * FF_ * 2);

  dim3 blk256(256);
  embed_kernel<<<M_, blk256, 0, stream>>>(x, embed, pos, h, hb);

  for (int l = 0; l < L_; ++l) {
    transpose_cast<<<dim3(3 * C_ / 32, C_ / 32), dim3(32, 8), 0, stream>>>(
        Wqkv + (size_t)l * C_ * 3 * C_, Wtqkv, C_, 3 * C_);
    transpose_cast2<<<dim3(FF_ / 32, C_ / 32, 2), dim3(32, 8), 0, stream>>>(
        W1a + (size_t)l * C_ * FF_, Wt1a, W1b + (size_t)l * C_ * FF_, Wt1b,
        C_, FF_);
    transpose_cast2<<<dim3(C_ / 32, FF_ / 32, 2), dim3(32, 8), 0, stream>>>(
        W2a + (size_t)l * FF_ * C_, Wt2a, W2b + (size_t)l * FF_ * C_, Wt2b,
        FF_, C_);

    gemm_bt<0, 1><<<dim3(3 * C_ / 128, M_ / 128), blk256, 0, stream>>>(
        hb, Wtqkv, bqkv + (size_t)l * 3 * C_, qkv, M_, 3 * C_, C_);
    vtrans_kernel<<<dim3(T_ / 32, D_HEAD / 32, B_ * H_), dim3(32, 8), 0,
                    stream>>>(qkv, vTb);
    attn_mfma<<<dim3(T_ / 64, B_ * H_), blk256, 0, stream>>>(qkv, vTb, ybuf);
    gemm_bt<1, 1><<<dim3(FF_ / 128, M_ / 128), blk256, 0, stream>>>(
        ybuf, Wt1a, b1a + (size_t)l * FF_, ubuf, M_, FF_, C_);
    gemm_bt<0, 0><<<dim3(C_ / 128, M_ / 128), blk256, 0, stream>>>(
        ubuf, Wt2a, b2a + (size_t)l * C_, zbuf, M_, C_, FF_);
    resid_ln<<<M_, blk256, 0, stream>>>(h, zbuf, g1 + (size_t)l * C_,
                                        be1 + (size_t)l * C_, hb);
    gemm_bt<1, 1><<<dim3(FF_ / 128, M_ / 128), blk256, 0, stream>>>(
        hb, Wt1b, b1b + (size_t)l * FF_, ubuf, M_, FF_, C_);
    gemm_bt<0, 0><<<dim3(C_ / 128, M_ / 128), blk256, 0, stream>>>(
        ubuf, Wt2b, b2b + (size_t)l * C_, zbuf, M_, C_, FF_);
    resid_ln<<<M_, blk256, 0, stream>>>(h, zbuf, g2 + (size_t)l * C_,
                                        be2 + (size_t)l * C_, hb);
  }

  transpose_cast<<<dim3(V_ / 32, C_ / 32), dim3(32, 8), 0, stream>>>(
      lmW, Wtqkv, C_, V_);
  gemm_bt<0, 0><<<dim3(V_ / 128, M_ / 128), blk256, 0, stream>>>(
      hb, Wtqkv, lmb, out, M_, V_, C_);
}